// Round 8
// baseline (874.033 us; speedup 1.0000x reference)
//
#include <hip/hip_runtime.h>

// Reorg (space-to-depth), stride 2.
// x:   (B=8, C=64, H=512, W=512) fp32
// out: (B=8, 4*C=256, H/2=256, W/2=256) fp32
// out[b][(sh*2+sw)*C + c][h2][w2] = x[b][c][2*h2+sh][2*w2+sw]
//
// Memory-bound permutation: 512 MiB read + 512 MiB write, roofline ~170 us.
// Per (thread, iteration): 8 consecutive input floats (two float4 loads,
// lane stride 32B -> every 64B line fully consumed across the pair);
// deinterleave even/odd -> two float4 stores (16B/lane, lane-contiguous,
// 1 KiB per store instruction, every output line written exactly once).
// Grid capped at 2048 blocks, grid-stride loop (32 uniform iters/thread).
// All shape math is shifts/masks (powers of two).

__global__ __launch_bounds__(256) void reorg_kernel(const float* __restrict__ x,
                                                    float* __restrict__ out) {
    // total 8-float chunks = B*C*H*W/8 = 16,777,216
    const unsigned total   = 8u * 64u * 512u * 512u / 8u;
    const unsigned nthread = gridDim.x * 256u;           // 524,288
    unsigned tid = blockIdx.x * 256u + threadIdx.x;

    #pragma unroll 4
    for (; tid < total; tid += nthread) {
        const unsigned t   = tid & 63u;    // 8-float chunk index in row (W/8 = 64)
        const unsigned row = tid >> 6;     // (b*C + c)*H + h

        const unsigned h  = row & 511u;    // H-1
        const unsigned bc = row >> 9;      // b*C + c
        const unsigned c  = bc & 63u;      // C-1
        const unsigned b  = bc >> 6;

        const unsigned h2 = h >> 1;
        const unsigned sh = h & 1u;

        const float* src = x + ((size_t)row << 9) + ((size_t)t << 3);
        const float4 v0 = *reinterpret_cast<const float4*>(src);      // w = 8t..8t+3
        const float4 v1 = *reinterpret_cast<const float4*>(src + 4);  // w = 8t+4..8t+7

        // sw=0 channel: sh*2*C + c = sh*128 + c ; sw=1 is +C (=+64*256*256 floats)
        const size_t ch0  = (size_t)b * 256u + (size_t)sh * 128u + c;
        const size_t base = (((ch0 << 8) + h2) << 8) + ((size_t)t << 2);

        const float4 ev = make_float4(v0.x, v0.z, v1.x, v1.z);  // sw=0: w2 = 4t..4t+3
        const float4 od = make_float4(v0.y, v0.w, v1.y, v1.w);  // sw=1: w2 = 4t..4t+3

        *reinterpret_cast<float4*>(out + base) = ev;
        *reinterpret_cast<float4*>(out + base + (size_t)64 * 256 * 256) = od;
    }
}

extern "C" void kernel_launch(void* const* d_in, const int* in_sizes, int n_in,
                              void* d_out, int out_size, void* d_ws, size_t ws_size,
                              hipStream_t stream) {
    const float* x = (const float*)d_in[0];
    float* out = (float*)d_out;

    reorg_kernel<<<2048, 256, 0, stream>>>(x, out);
}